// Round 12
// baseline (2089.423 us; speedup 1.0000x reference)
//
#include <hip/hip_runtime.h>

// ---------------------------------------------------------------------------
// MattingSolver CG on MI355X — round 12: R10 verbatim + ONE change:
// k_it2 gets 2 threads/row (contiguous halves, width-2 shfl combine),
// grid 576 -> 1152 blocks.
//
// R11 (three simultaneous changes) tripped the graph-divergence tripwire with
// a layout identical to R10's; cause not identifiable by inspection -> bisect
// by construction: minimal delta from the proven 1862us R10 kernel. it2 is
// the occupancy-worst kernel (576 blocks = 2.25/CU = 28% thread slots).
//
// Segments: seg0 CM by row -> csrPk (NNZ) | seg1 CM by col -> cscPk (NNZ)
//           seg2 unified u by out-row -> gU (15*NLOC)
// u_all: [0,9NL) Wm | [9NL,14NL) -uA dirB | [14NL,15NL) uAsum dirA.
// ws ~40.8 MB (< proven 43.4). scal: rs_t at [t], pAp_t at [40+t].
// ---------------------------------------------------------------------------

#define TPB 256

__device__ __forceinline__ float blockReduce256(float v) {
  #pragma unroll
  for (int o = 32; o > 0; o >>= 1) v += __shfl_down(v, o, 64);
  __shared__ float s[4];
  int lane = threadIdx.x & 63, wv = threadIdx.x >> 6;
  if (lane == 0) s[wv] = v;
  __syncthreads();
  return (threadIdx.x == 0) ? (s[0] + s[1] + s[2] + s[3]) : 0.f;
}

// vectors, diag, b, scal, CNT zero, b.b  (grid: 3*Bn)
__global__ void k_init0(const float* __restrict__ KUw, const float* __restrict__ kToUconf,
                        const float* __restrict__ lmbda, const float* __restrict__ known,
                        const float* __restrict__ kToU,
                        float* __restrict__ diag_ku, float* __restrict__ r,
                        float* __restrict__ p, float* __restrict__ x,
                        int* __restrict__ CNT, float* __restrict__ scal, int N)
{
  int i = blockIdx.x * TPB + threadIdx.x;
  if (i < 80) scal[i] = 0.f;
  if (i < 3 * N) CNT[i] = 0;
  float red = 0.f;
  if (i < N) {
    float dk = KUw[i] * kToUconf[i] + lmbda[0] * known[i];
    diag_ku[i] = dk;
    float b = dk * kToU[i];
    r[i] = b; p[i] = b; x[i] = 0.f;
    red = b * b;
  }
  float v = blockReduce256(red);
  if (threadIdx.x == 0) atomicAdd(&scal[0], v);
}

// in-place symmetrization: LOC_flows rows 0..35 <- 0.5*w*(F_ab+F_ba), a<b.
// Thread k owns column k; harness restores d_in before every launch.
__global__ void k_prep(float* __restrict__ LOC_flows, const int* __restrict__ LOC_inInd,
                       const float* __restrict__ LOCw, int NLOC)
{
  int k = blockIdx.x * TPB + threadIdx.x;
  float Fl[81];
  #pragma unroll
  for (int m = 0; m < 81; ++m) Fl[m] = LOC_flows[(size_t)m * NLOC + k];
  float hw = 0.5f * LOCw[LOC_inInd[k]];
  int idx = 0;
  #pragma unroll
  for (int a = 0; a < 9; ++a)
    #pragma unroll
    for (int b = a + 1; b < 9; ++b) {
      LOC_flows[(size_t)idx * NLOC + k] = hw * (Fl[a * 9 + b] + Fl[b * 9 + a]);
      ++idx;
    }
}

// histograms + tickets  (grid: Bz + Bl + Bl)
__global__ void k_hist(const int* __restrict__ Wrow, const int* __restrict__ Wcol,
                       const int* __restrict__ LOC_inInd, const int* __restrict__ width_p,
                       const int* __restrict__ IU_inInd, const int* __restrict__ IU_neighInd,
                       int* __restrict__ CNT,
                       unsigned short* __restrict__ tr, unsigned short* __restrict__ tc,
                       unsigned short* __restrict__ tU,
                       int NLOC, int N, int B0, int B1)
{
  int blk = blockIdx.x;
  if (blk < B0) {
    int e = blk * TPB + threadIdx.x;
    tr[e] = (unsigned short)atomicAdd(&CNT[Wrow[e]], 1);
    tc[e] = (unsigned short)atomicAdd(&CNT[N + Wcol[e]], 1);
  } else if (blk < B1) {                // Wm: (k,a) by out-row
    int k = (blk - B0) * TPB + threadIdx.x;
    int wd = *width_p;
    int base = LOC_inInd[k];
    const int offs[9] = {-1 - wd, -1, -1 + wd, -wd, 0, wd, 1 - wd, 1, 1 + wd};
    #pragma unroll
    for (int a = 0; a < 9; ++a)
      tU[a * NLOC + k] = (unsigned short)atomicAdd(&CNT[2 * N + base + offs[a]], 1);
  } else {                              // Wc: dirA k by r0, dirB (k,j) by c0
    int k = (blk - B1) * TPB + threadIdx.x;
    tU[14 * NLOC + k] = (unsigned short)atomicAdd(&CNT[2 * N + IU_inInd[k]], 1);
    #pragma unroll
    for (int j = 0; j < 5; ++j)
      tU[(9 + j) * NLOC + k] =
          (unsigned short)atomicAdd(&CNT[2 * N + IU_neighInd[k * 5 + j]], 1);
  }
}

// in-place exclusive scan (OFF==CNT)
__global__ void k_scan1(int* __restrict__ OFF, int* __restrict__ bsum, int tot)
{
  __shared__ int s[TPB];
  int gid = blockIdx.x * TPB + threadIdx.x;
  int v = (gid < tot) ? OFF[gid] : 0;
  s[threadIdx.x] = v;
  __syncthreads();
  #pragma unroll
  for (int o = 1; o < TPB; o <<= 1) {
    int t = (threadIdx.x >= o) ? s[threadIdx.x - o] : 0;
    __syncthreads();
    s[threadIdx.x] += t;
    __syncthreads();
  }
  if (gid < tot) OFF[gid] = s[threadIdx.x] - v;
  if (threadIdx.x == TPB - 1) bsum[blockIdx.x] = s[threadIdx.x];
}

__global__ void k_scan2(int* __restrict__ bsum, int nPerArr)  // 3 blocks x 1024
{
  __shared__ int s[1024];
  int base = blockIdx.x * nPerArr;
  int v = (threadIdx.x < nPerArr) ? bsum[base + threadIdx.x] : 0;
  s[threadIdx.x] = v;
  __syncthreads();
  for (int o = 1; o < 1024; o <<= 1) {
    int t = (threadIdx.x >= o) ? s[threadIdx.x - o] : 0;
    __syncthreads();
    s[threadIdx.x] += t;
    __syncthreads();
  }
  if (threadIdx.x < nPerArr) bsum[base + threadIdx.x] = s[threadIdx.x] - v;
}

__global__ void k_scan3(int* __restrict__ OFF, const int* __restrict__ bsum, int tot)
{
  int gid = blockIdx.x * TPB + threadIdx.x;
  if (gid < tot) OFF[gid] += bsum[blockIdx.x];
}

// atomic-free fill: pos = OFF[key] + ticket  (grid: Bz + Bl + Bl)
__global__ void k_fill(const float* __restrict__ CMw, const float* __restrict__ Wcm_data,
                       const int* __restrict__ Wrow, const int* __restrict__ Wcol,
                       const int* __restrict__ LOC_inInd, const int* __restrict__ width_p,
                       const int* __restrict__ IU_inInd, const int* __restrict__ IU_neighInd,
                       const int* __restrict__ OFF,
                       const unsigned short* __restrict__ tr, const unsigned short* __restrict__ tc,
                       const unsigned short* __restrict__ tU,
                       int2* __restrict__ csrPk, int2* __restrict__ cscPk,
                       int* __restrict__ gU,
                       int NLOC, int N, int B0, int B1)
{
  int blk = blockIdx.x;
  if (blk < B0) {
    int e = blk * TPB + threadIdx.x;
    int row = Wrow[e], col = Wcol[e];
    int cv = __float_as_int(CMw[row] * Wcm_data[e]);
    csrPk[OFF[row] + tr[e]] = make_int2(col, cv);
    cscPk[OFF[N + col] + tc[e]] = make_int2(row, cv);
  } else if (blk < B1) {
    int k = (blk - B0) * TPB + threadIdx.x;
    int wd = *width_p;
    int base = LOC_inInd[k];
    const int offs[9] = {-1 - wd, -1, -1 + wd, -wd, 0, wd, 1 - wd, 1, 1 + wd};
    #pragma unroll
    for (int a = 0; a < 9; ++a)
      gU[OFF[2 * N + base + offs[a]] + tU[a * NLOC + k]] = a * NLOC + k;
  } else {
    int k = (blk - B1) * TPB + threadIdx.x;
    gU[OFF[2 * N + IU_inInd[k]] + tU[14 * NLOC + k]] = 14 * NLOC + k;
    #pragma unroll
    for (int j = 0; j < 5; ++j)
      gU[OFF[2 * N + IU_neighInd[k * 5 + j]] + tU[(9 + j) * NLOC + k]] =
          (9 + j) * NLOC + k;
  }
}

// pass 1: Wm (S2 pairs) / Wc products -> u_all; CSR Lv/rs_cm (8-wide); pAp
// grid: Bl + Bl + Bn   (UNCHANGED from R10)
__global__ void k_it1(const float* __restrict__ p,
                      const float* __restrict__ S2, const int* __restrict__ LOC_inInd,
                      const int* __restrict__ width_p,
                      const float* __restrict__ IU_flows, const int* __restrict__ IU_inInd,
                      const int* __restrict__ IU_neighInd, const float* __restrict__ IUw,
                      const float* __restrict__ diag_ku,
                      const int* __restrict__ OFF, const int2* __restrict__ csrPk,
                      float* __restrict__ u_all,
                      float* __restrict__ Lv, float* __restrict__ rs_cm,
                      float* __restrict__ pAp_t,
                      int NNZ, int NLOC, int N, int B0, int B1)
{
  int blk = blockIdx.x;
  float red = 0.f;
  if (blk < B0) {                       // Wm via symmetric pair coefficients
    int k = blk * TPB + threadIdx.x;
    int wd = *width_p;
    int base = LOC_inInd[k];
    const int offs[9] = {-1 - wd, -1, -1 + wd, -wd, 0, wd, 1 - wd, 1, 1 + wd};
    float pv[9];
    #pragma unroll
    for (int a = 0; a < 9; ++a) pv[a] = p[base + offs[a]];
    float u[9] = {0.f, 0.f, 0.f, 0.f, 0.f, 0.f, 0.f, 0.f, 0.f};
    float qf = 0.f;
    int idx = 0;
    #pragma unroll
    for (int a = 0; a < 9; ++a)
      #pragma unroll
      for (int b = a + 1; b < 9; ++b) {
        float sv = S2[(size_t)idx * NLOC + k];
        ++idx;
        float d = pv[a] - pv[b];
        float t = sv * d;
        u[a] += t; u[b] -= t;
        qf += t * d;
      }
    #pragma unroll
    for (int a = 0; a < 9; ++a) u_all[a * NLOC + k] = u[a];
    red = qf;
  } else if (blk < B1) {                // Wc
    int k = (blk - B0) * TPB + threadIdx.x;
    int r0 = IU_inInd[k];
    float hw = 0.5f * IUw[r0];
    float pr = p[r0];
    int c[5]; float w[5];
    #pragma unroll
    for (int j = 0; j < 5; ++j) {
      c[j] = IU_neighInd[k * 5 + j];
      w[j] = hw * IU_flows[k * 5 + j];
    }
    float pc[5];
    #pragma unroll
    for (int j = 0; j < 5; ++j) pc[j] = p[c[j]];
    float qf = 0.f, asum = 0.f;
    #pragma unroll
    for (int j = 0; j < 5; ++j) {
      float d = pr - pc[j];
      float uA = w[j] * d;
      u_all[(9 + j) * NLOC + k] = -uA;   // direction B (row c0)
      asum += uA;
      qf += uA * d;
    }
    u_all[14 * NLOC + k] = asum;          // direction A row-sum (row r0)
    red = qf;
  } else {                              // CSR: Lv = sum cv (p_i - p_c), 8-wide
    int i = (blk - B1) * TPB + threadIdx.x;
    float pi = p[i];
    int s = OFF[i];
    int e = (i == N - 1) ? NNZ : OFF[i + 1];
    float acc = 0.f, rs = 0.f;
    int q = s;
    for (; q + 8 <= e; q += 8) {
      int2 ed[8];
      #pragma unroll
      for (int m = 0; m < 8; ++m) ed[m] = csrPk[q + m];
      float g[8];
      #pragma unroll
      for (int m = 0; m < 8; ++m) g[m] = p[ed[m].x];
      #pragma unroll
      for (int m = 0; m < 8; ++m) {
        float cv = __int_as_float(ed[m].y);
        rs += cv;
        acc += cv * (pi - g[m]);
      }
    }
    for (; q + 4 <= e; q += 4) {
      int2 ed[4];
      #pragma unroll
      for (int m = 0; m < 4; ++m) ed[m] = csrPk[q + m];
      float g[4];
      #pragma unroll
      for (int m = 0; m < 4; ++m) g[m] = p[ed[m].x];
      #pragma unroll
      for (int m = 0; m < 4; ++m) {
        float cv = __int_as_float(ed[m].y);
        rs += cv;
        acc += cv * (pi - g[m]);
      }
    }
    for (; q < e; ++q) {
      int2 ed = csrPk[q];
      float cv = __int_as_float(ed.y);
      rs += cv;
      acc += cv * (pi - p[ed.x]);
    }
    Lv[i] = acc;
    rs_cm[i] = rs;
    red = diag_ku[i] * pi * pi + acc * acc;
  }
  float v = blockReduce256(red);
  if (threadIdx.x == 0) atomicAdd(pAp_t, v);
}

// pass 2: Ap assembly — 2 threads/row, contiguous halves (THE one change).
// grid: 2*Bn
__global__ void k_it2(float* __restrict__ x, float* __restrict__ r,
                      const float* __restrict__ p, const float* __restrict__ Lv,
                      const float* __restrict__ rs_cm, const float* __restrict__ diag_ku,
                      const int* __restrict__ OFF,
                      const int2* __restrict__ cscPk,
                      const int* __restrict__ gU, const float* __restrict__ u_all,
                      const float* __restrict__ rs_t, const float* __restrict__ pAp_t,
                      float* __restrict__ rs_t1,
                      int NNZ, int NLOC, int N)
{
  int g = blockIdx.x * TPB + threadIdx.x;
  int i = g >> 1, half = g & 1;
  float alpha = rs_t[0] / pAp_t[0];
  float tg = 0.f;
  // unified u-pull (Wm + WcA + WcB), contiguous half, 4/1-wide
  {
    int s0 = OFF[2 * N + i];
    int e0 = (i == N - 1) ? 15 * NLOC : OFF[2 * N + i + 1];
    int mid = (s0 + e0) >> 1;
    int lo = half ? mid : s0;
    int hi = half ? e0 : mid;
    int q = lo;
    for (; q + 4 <= hi; q += 4) {
      int gg[4];
      #pragma unroll
      for (int m = 0; m < 4; ++m) gg[m] = gU[q + m];
      float u[4];
      #pragma unroll
      for (int m = 0; m < 4; ++m) u[m] = u_all[gg[m]];
      #pragma unroll
      for (int m = 0; m < 4; ++m) tg += u[m];
    }
    for (; q < hi; ++q) tg += u_all[gU[q]];
  }
  // CM: W^T Lv via CSC, contiguous half, 4/1-wide
  float sc = 0.f;
  {
    int s0 = OFF[N + i];
    int e0 = (i == N - 1) ? NNZ : OFF[N + i + 1];
    int mid = (s0 + e0) >> 1;
    int lo = half ? mid : s0;
    int hi = half ? e0 : mid;
    int q = lo;
    for (; q + 4 <= hi; q += 4) {
      int2 ed[4];
      #pragma unroll
      for (int m = 0; m < 4; ++m) ed[m] = cscPk[q + m];
      float l[4];
      #pragma unroll
      for (int m = 0; m < 4; ++m) l[m] = Lv[ed[m].x];
      #pragma unroll
      for (int m = 0; m < 4; ++m) sc += __int_as_float(ed[m].y) * l[m];
    }
    for (; q < hi; ++q) {
      int2 ed = cscPk[q];
      sc += __int_as_float(ed.y) * Lv[ed.x];
    }
  }
  tg += __shfl_down(tg, 1, 2);
  sc += __shfl_down(sc, 1, 2);
  float red = 0.f;
  if (!half) {
    float pi = p[i];
    float Ap = diag_ku[i] * pi + rs_cm[i] * Lv[i] - sc + tg;
    x[i] += alpha * pi;
    float rn = r[i] - alpha * Ap;
    r[i] = rn;
    red = rn * rn;
  }
  float v = blockReduce256(red);
  if (threadIdx.x == 0) atomicAdd(rs_t1, v);
}

__global__ void k_it3(float* __restrict__ p, const float* __restrict__ r,
                      const float* __restrict__ rs_new, const float* __restrict__ rs_old, int N)
{
  int i = blockIdx.x * TPB + threadIdx.x;
  float beta = rs_new[0] / rs_old[0];
  p[i] = r[i] + beta * p[i];
}

extern "C" void kernel_launch(void* const* d_in, const int* in_sizes, int n_in,
                              void* d_out, int out_size, void* d_ws, size_t ws_size,
                              hipStream_t stream)
{
  const float* CMw       = (const float*)d_in[0];
  const float* LOCw      = (const float*)d_in[1];
  const float* IUw       = (const float*)d_in[2];
  const float* KUw       = (const float*)d_in[3];
  const float* lmbda     = (const float*)d_in[4];
  const float* kToUconf  = (const float*)d_in[5];
  const float* known     = (const float*)d_in[6];
  const float* kToU      = (const float*)d_in[7];
  const float* Wcm_data  = (const float*)d_in[8];
  float*       LOC_flows = (float*)d_in[9];      // overwritten in-place by k_prep;
                                                 // harness restores d_in every launch
  const float* IU_flows  = (const float*)d_in[10];
  const int*   Wrow      = (const int*)d_in[11];
  const int*   Wcol      = (const int*)d_in[12];
  const int*   LOC_inInd = (const int*)d_in[13];
  const int*   IU_inInd  = (const int*)d_in[14];
  const int*   IU_neighInd = (const int*)d_in[15];
  const int*   width_p   = (const int*)d_in[16];
  const int CG_STEPS = 30;

  const int N    = in_sizes[0];      // 147456 (% 256 == 0)
  const int NNZ  = in_sizes[8];      // 1474560
  const int NLOC = in_sizes[13];     // 73728

  // ---- workspace layout, ~40.8 MB (identical to R10) ----
  float* x       = (float*)d_out;
  float* r       = (float*)d_ws;                 // N
  float* p       = r + N;                        // N
  float* Lv      = p + N;                        // N
  float* rs_cm   = Lv + N;                       // N
  float* diag_ku = rs_cm + N;                    // N
  int2*  csrPk   = (int2*)(diag_ku + N);         // NNZ int2
  int2*  cscPk   = csrPk + (size_t)NNZ;          // NNZ int2
  int*   gU      = (int*)(cscPk + (size_t)NNZ);  // 15*NLOC
  int*   OFF     = gU + (size_t)15 * NLOC;       // 3N (in-place CNT -> OFF)
  unsigned short* tr = (unsigned short*)(OFF + (size_t)3 * N);  // NNZ u16
  unsigned short* tc = tr + (size_t)NNZ;         // NNZ u16
  unsigned short* tU = tc + (size_t)NNZ;         // 15*NLOC u16
  float* u_all   = (float*)tr;                   // 15*NLOC floats, aliases tickets
                                                 // (tickets dead after k_fill)
  int*   bsum    = (int*)(tU + (size_t)15 * NLOC);  // 3*(N/256)
  float* scal    = (float*)(bsum + 3 * (N / TPB));  // 80 floats

  const int Bn = N / TPB;        // 576
  const int Bz = NNZ / TPB;      // 5760
  const int Bl = NLOC / TPB;     // 288
  const int Z3 = 3 * Bn;

  k_init0<<<Z3, TPB, 0, stream>>>(KUw, kToUconf, lmbda, known, kToU,
                                  diag_ku, r, p, x, OFF, scal, N);
  k_prep<<<Bl, TPB, 0, stream>>>(LOC_flows, LOC_inInd, LOCw, NLOC);
  k_hist<<<Bz + 2 * Bl, TPB, 0, stream>>>(Wrow, Wcol, LOC_inInd, width_p,
                                          IU_inInd, IU_neighInd, OFF,
                                          tr, tc, tU, NLOC, N, Bz, Bz + Bl);
  k_scan1<<<Z3, TPB, 0, stream>>>(OFF, bsum, 3 * N);
  k_scan2<<<3, 1024, 0, stream>>>(bsum, Bn);
  k_scan3<<<Z3, TPB, 0, stream>>>(OFF, bsum, 3 * N);
  k_fill<<<Bz + 2 * Bl, TPB, 0, stream>>>(CMw, Wcm_data, Wrow, Wcol,
                                          LOC_inInd, width_p, IU_inInd, IU_neighInd,
                                          OFF, tr, tc, tU,
                                          csrPk, cscPk, gU,
                                          NLOC, N, Bz, Bz + Bl);

  for (int t = 0; t < CG_STEPS; ++t) {
    k_it1<<<2 * Bl + Bn, TPB, 0, stream>>>(
        p, LOC_flows, LOC_inInd, width_p,
        IU_flows, IU_inInd, IU_neighInd, IUw,
        diag_ku, OFF, csrPk, u_all, Lv, rs_cm, scal + 40 + t,
        NNZ, NLOC, N, Bl, 2 * Bl);
    k_it2<<<2 * Bn, TPB, 0, stream>>>(
        x, r, p, Lv, rs_cm, diag_ku, OFF, cscPk, gU, u_all,
        scal + t, scal + 40 + t, scal + t + 1, NNZ, NLOC, N);
    if (t + 1 < CG_STEPS)
      k_it3<<<Bn, TPB, 0, stream>>>(p, r, scal + t + 1, scal + t, N);
  }
}

// Round 13
// 1879.480 us; speedup vs baseline: 1.1117x; 1.1117x over previous
//
#include <hip/hip_runtime.h>

// ---------------------------------------------------------------------------
// MattingSolver CG on MI355X — round 13: restore R10 verbatim (measured best,
// 1862us). R12's bisect proved the 2-thr/row it2 split correct but slower
// (1862->2089): iteration kernels are at a gather-issue floor, not
// occupancy-bound (refuted twice: R4, R12). Setup hist is at the atomic wall
// (4.06M returning atomics, ~160us). This configuration is the converged
// optimum of the family; all catalog levers tested (see session journal).
//
// Segments: seg0 CM by row -> csrPk (NNZ) | seg1 CM by col -> cscPk (NNZ)
//           seg2 unified u by out-row -> gU (15*NLOC)
// u_all: [0,9NL) Wm | [9NL,14NL) -uA dirB | [14NL,15NL) uAsum dirA.
// ws ~40.8 MB (< proven 43.4). scal: rs_t at [t], pAp_t at [40+t].
// ---------------------------------------------------------------------------

#define TPB 256

__device__ __forceinline__ float blockReduce256(float v) {
  #pragma unroll
  for (int o = 32; o > 0; o >>= 1) v += __shfl_down(v, o, 64);
  __shared__ float s[4];
  int lane = threadIdx.x & 63, wv = threadIdx.x >> 6;
  if (lane == 0) s[wv] = v;
  __syncthreads();
  return (threadIdx.x == 0) ? (s[0] + s[1] + s[2] + s[3]) : 0.f;
}

// vectors, diag, b, scal, CNT zero, b.b  (grid: 3*Bn)
__global__ void k_init0(const float* __restrict__ KUw, const float* __restrict__ kToUconf,
                        const float* __restrict__ lmbda, const float* __restrict__ known,
                        const float* __restrict__ kToU,
                        float* __restrict__ diag_ku, float* __restrict__ r,
                        float* __restrict__ p, float* __restrict__ x,
                        int* __restrict__ CNT, float* __restrict__ scal, int N)
{
  int i = blockIdx.x * TPB + threadIdx.x;
  if (i < 80) scal[i] = 0.f;
  if (i < 3 * N) CNT[i] = 0;
  float red = 0.f;
  if (i < N) {
    float dk = KUw[i] * kToUconf[i] + lmbda[0] * known[i];
    diag_ku[i] = dk;
    float b = dk * kToU[i];
    r[i] = b; p[i] = b; x[i] = 0.f;
    red = b * b;
  }
  float v = blockReduce256(red);
  if (threadIdx.x == 0) atomicAdd(&scal[0], v);
}

// in-place symmetrization: LOC_flows rows 0..35 <- 0.5*w*(F_ab+F_ba), a<b.
// Thread k owns column k; harness restores d_in before every launch.
__global__ void k_prep(float* __restrict__ LOC_flows, const int* __restrict__ LOC_inInd,
                       const float* __restrict__ LOCw, int NLOC)
{
  int k = blockIdx.x * TPB + threadIdx.x;
  float Fl[81];
  #pragma unroll
  for (int m = 0; m < 81; ++m) Fl[m] = LOC_flows[(size_t)m * NLOC + k];
  float hw = 0.5f * LOCw[LOC_inInd[k]];
  int idx = 0;
  #pragma unroll
  for (int a = 0; a < 9; ++a)
    #pragma unroll
    for (int b = a + 1; b < 9; ++b) {
      LOC_flows[(size_t)idx * NLOC + k] = hw * (Fl[a * 9 + b] + Fl[b * 9 + a]);
      ++idx;
    }
}

// histograms + tickets  (grid: Bz + Bl + Bl)
__global__ void k_hist(const int* __restrict__ Wrow, const int* __restrict__ Wcol,
                       const int* __restrict__ LOC_inInd, const int* __restrict__ width_p,
                       const int* __restrict__ IU_inInd, const int* __restrict__ IU_neighInd,
                       int* __restrict__ CNT,
                       unsigned short* __restrict__ tr, unsigned short* __restrict__ tc,
                       unsigned short* __restrict__ tU,
                       int NLOC, int N, int B0, int B1)
{
  int blk = blockIdx.x;
  if (blk < B0) {
    int e = blk * TPB + threadIdx.x;
    tr[e] = (unsigned short)atomicAdd(&CNT[Wrow[e]], 1);
    tc[e] = (unsigned short)atomicAdd(&CNT[N + Wcol[e]], 1);
  } else if (blk < B1) {                // Wm: (k,a) by out-row
    int k = (blk - B0) * TPB + threadIdx.x;
    int wd = *width_p;
    int base = LOC_inInd[k];
    const int offs[9] = {-1 - wd, -1, -1 + wd, -wd, 0, wd, 1 - wd, 1, 1 + wd};
    #pragma unroll
    for (int a = 0; a < 9; ++a)
      tU[a * NLOC + k] = (unsigned short)atomicAdd(&CNT[2 * N + base + offs[a]], 1);
  } else {                              // Wc: dirA k by r0, dirB (k,j) by c0
    int k = (blk - B1) * TPB + threadIdx.x;
    tU[14 * NLOC + k] = (unsigned short)atomicAdd(&CNT[2 * N + IU_inInd[k]], 1);
    #pragma unroll
    for (int j = 0; j < 5; ++j)
      tU[(9 + j) * NLOC + k] =
          (unsigned short)atomicAdd(&CNT[2 * N + IU_neighInd[k * 5 + j]], 1);
  }
}

// in-place exclusive scan (OFF==CNT)
__global__ void k_scan1(int* __restrict__ OFF, int* __restrict__ bsum, int tot)
{
  __shared__ int s[TPB];
  int gid = blockIdx.x * TPB + threadIdx.x;
  int v = (gid < tot) ? OFF[gid] : 0;
  s[threadIdx.x] = v;
  __syncthreads();
  #pragma unroll
  for (int o = 1; o < TPB; o <<= 1) {
    int t = (threadIdx.x >= o) ? s[threadIdx.x - o] : 0;
    __syncthreads();
    s[threadIdx.x] += t;
    __syncthreads();
  }
  if (gid < tot) OFF[gid] = s[threadIdx.x] - v;
  if (threadIdx.x == TPB - 1) bsum[blockIdx.x] = s[threadIdx.x];
}

__global__ void k_scan2(int* __restrict__ bsum, int nPerArr)  // 3 blocks x 1024
{
  __shared__ int s[1024];
  int base = blockIdx.x * nPerArr;
  int v = (threadIdx.x < nPerArr) ? bsum[base + threadIdx.x] : 0;
  s[threadIdx.x] = v;
  __syncthreads();
  for (int o = 1; o < 1024; o <<= 1) {
    int t = (threadIdx.x >= o) ? s[threadIdx.x - o] : 0;
    __syncthreads();
    s[threadIdx.x] += t;
    __syncthreads();
  }
  if (threadIdx.x < nPerArr) bsum[base + threadIdx.x] = s[threadIdx.x] - v;
}

__global__ void k_scan3(int* __restrict__ OFF, const int* __restrict__ bsum, int tot)
{
  int gid = blockIdx.x * TPB + threadIdx.x;
  if (gid < tot) OFF[gid] += bsum[blockIdx.x];
}

// atomic-free fill: pos = OFF[key] + ticket  (grid: Bz + Bl + Bl)
__global__ void k_fill(const float* __restrict__ CMw, const float* __restrict__ Wcm_data,
                       const int* __restrict__ Wrow, const int* __restrict__ Wcol,
                       const int* __restrict__ LOC_inInd, const int* __restrict__ width_p,
                       const int* __restrict__ IU_inInd, const int* __restrict__ IU_neighInd,
                       const int* __restrict__ OFF,
                       const unsigned short* __restrict__ tr, const unsigned short* __restrict__ tc,
                       const unsigned short* __restrict__ tU,
                       int2* __restrict__ csrPk, int2* __restrict__ cscPk,
                       int* __restrict__ gU,
                       int NLOC, int N, int B0, int B1)
{
  int blk = blockIdx.x;
  if (blk < B0) {
    int e = blk * TPB + threadIdx.x;
    int row = Wrow[e], col = Wcol[e];
    int cv = __float_as_int(CMw[row] * Wcm_data[e]);
    csrPk[OFF[row] + tr[e]] = make_int2(col, cv);
    cscPk[OFF[N + col] + tc[e]] = make_int2(row, cv);
  } else if (blk < B1) {
    int k = (blk - B0) * TPB + threadIdx.x;
    int wd = *width_p;
    int base = LOC_inInd[k];
    const int offs[9] = {-1 - wd, -1, -1 + wd, -wd, 0, wd, 1 - wd, 1, 1 + wd};
    #pragma unroll
    for (int a = 0; a < 9; ++a)
      gU[OFF[2 * N + base + offs[a]] + tU[a * NLOC + k]] = a * NLOC + k;
  } else {
    int k = (blk - B1) * TPB + threadIdx.x;
    gU[OFF[2 * N + IU_inInd[k]] + tU[14 * NLOC + k]] = 14 * NLOC + k;
    #pragma unroll
    for (int j = 0; j < 5; ++j)
      gU[OFF[2 * N + IU_neighInd[k * 5 + j]] + tU[(9 + j) * NLOC + k]] =
          (9 + j) * NLOC + k;
  }
}

// pass 1: Wm (S2 pairs) / Wc products -> u_all; CSR Lv/rs_cm (8-wide); pAp
// grid: Bl + Bl + Bn
__global__ void k_it1(const float* __restrict__ p,
                      const float* __restrict__ S2, const int* __restrict__ LOC_inInd,
                      const int* __restrict__ width_p,
                      const float* __restrict__ IU_flows, const int* __restrict__ IU_inInd,
                      const int* __restrict__ IU_neighInd, const float* __restrict__ IUw,
                      const float* __restrict__ diag_ku,
                      const int* __restrict__ OFF, const int2* __restrict__ csrPk,
                      float* __restrict__ u_all,
                      float* __restrict__ Lv, float* __restrict__ rs_cm,
                      float* __restrict__ pAp_t,
                      int NNZ, int NLOC, int N, int B0, int B1)
{
  int blk = blockIdx.x;
  float red = 0.f;
  if (blk < B0) {                       // Wm via symmetric pair coefficients
    int k = blk * TPB + threadIdx.x;
    int wd = *width_p;
    int base = LOC_inInd[k];
    const int offs[9] = {-1 - wd, -1, -1 + wd, -wd, 0, wd, 1 - wd, 1, 1 + wd};
    float pv[9];
    #pragma unroll
    for (int a = 0; a < 9; ++a) pv[a] = p[base + offs[a]];
    float u[9] = {0.f, 0.f, 0.f, 0.f, 0.f, 0.f, 0.f, 0.f, 0.f};
    float qf = 0.f;
    int idx = 0;
    #pragma unroll
    for (int a = 0; a < 9; ++a)
      #pragma unroll
      for (int b = a + 1; b < 9; ++b) {
        float sv = S2[(size_t)idx * NLOC + k];
        ++idx;
        float d = pv[a] - pv[b];
        float t = sv * d;
        u[a] += t; u[b] -= t;
        qf += t * d;
      }
    #pragma unroll
    for (int a = 0; a < 9; ++a) u_all[a * NLOC + k] = u[a];
    red = qf;
  } else if (blk < B1) {                // Wc
    int k = (blk - B0) * TPB + threadIdx.x;
    int r0 = IU_inInd[k];
    float hw = 0.5f * IUw[r0];
    float pr = p[r0];
    int c[5]; float w[5];
    #pragma unroll
    for (int j = 0; j < 5; ++j) {
      c[j] = IU_neighInd[k * 5 + j];
      w[j] = hw * IU_flows[k * 5 + j];
    }
    float pc[5];
    #pragma unroll
    for (int j = 0; j < 5; ++j) pc[j] = p[c[j]];
    float qf = 0.f, asum = 0.f;
    #pragma unroll
    for (int j = 0; j < 5; ++j) {
      float d = pr - pc[j];
      float uA = w[j] * d;
      u_all[(9 + j) * NLOC + k] = -uA;   // direction B (row c0)
      asum += uA;
      qf += uA * d;
    }
    u_all[14 * NLOC + k] = asum;          // direction A row-sum (row r0)
    red = qf;
  } else {                              // CSR: Lv = sum cv (p_i - p_c), 8-wide
    int i = (blk - B1) * TPB + threadIdx.x;
    float pi = p[i];
    int s = OFF[i];
    int e = (i == N - 1) ? NNZ : OFF[i + 1];
    float acc = 0.f, rs = 0.f;
    int q = s;
    for (; q + 8 <= e; q += 8) {
      int2 ed[8];
      #pragma unroll
      for (int m = 0; m < 8; ++m) ed[m] = csrPk[q + m];
      float g[8];
      #pragma unroll
      for (int m = 0; m < 8; ++m) g[m] = p[ed[m].x];
      #pragma unroll
      for (int m = 0; m < 8; ++m) {
        float cv = __int_as_float(ed[m].y);
        rs += cv;
        acc += cv * (pi - g[m]);
      }
    }
    for (; q + 4 <= e; q += 4) {
      int2 ed[4];
      #pragma unroll
      for (int m = 0; m < 4; ++m) ed[m] = csrPk[q + m];
      float g[4];
      #pragma unroll
      for (int m = 0; m < 4; ++m) g[m] = p[ed[m].x];
      #pragma unroll
      for (int m = 0; m < 4; ++m) {
        float cv = __int_as_float(ed[m].y);
        rs += cv;
        acc += cv * (pi - g[m]);
      }
    }
    for (; q < e; ++q) {
      int2 ed = csrPk[q];
      float cv = __int_as_float(ed.y);
      rs += cv;
      acc += cv * (pi - p[ed.x]);
    }
    Lv[i] = acc;
    rs_cm[i] = rs;
    red = diag_ku[i] * pi * pi + acc * acc;
  }
  float v = blockReduce256(red);
  if (threadIdx.x == 0) atomicAdd(pAp_t, v);
}

// pass 2: Ap = diag p + rs_cm Lv - csc_pull(Lv) + unified u-pull; x/r; r.r
__global__ void k_it2(float* __restrict__ x, float* __restrict__ r,
                      const float* __restrict__ p, const float* __restrict__ Lv,
                      const float* __restrict__ rs_cm, const float* __restrict__ diag_ku,
                      const int* __restrict__ OFF,
                      const int2* __restrict__ cscPk,
                      const int* __restrict__ gU, const float* __restrict__ u_all,
                      const float* __restrict__ rs_t, const float* __restrict__ pAp_t,
                      float* __restrict__ rs_t1,
                      int NNZ, int NLOC, int N)
{
  int i = blockIdx.x * TPB + threadIdx.x;
  float alpha = rs_t[0] / pAp_t[0];
  float tg = 0.f;
  // unified u-pull (Wm + WcA + WcB), 8/4/1-wide
  {
    int s0 = OFF[2 * N + i];
    int e0 = (i == N - 1) ? 15 * NLOC : OFF[2 * N + i + 1];
    int q = s0;
    for (; q + 8 <= e0; q += 8) {
      int g[8];
      #pragma unroll
      for (int m = 0; m < 8; ++m) g[m] = gU[q + m];
      float u[8];
      #pragma unroll
      for (int m = 0; m < 8; ++m) u[m] = u_all[g[m]];
      #pragma unroll
      for (int m = 0; m < 8; ++m) tg += u[m];
    }
    for (; q + 4 <= e0; q += 4) {
      int g[4];
      #pragma unroll
      for (int m = 0; m < 4; ++m) g[m] = gU[q + m];
      float u[4];
      #pragma unroll
      for (int m = 0; m < 4; ++m) u[m] = u_all[g[m]];
      #pragma unroll
      for (int m = 0; m < 4; ++m) tg += u[m];
    }
    for (; q < e0; ++q) tg += u_all[gU[q]];
  }
  // CM: W^T Lv via CSC, 8/4/1-wide
  float sc = 0.f;
  {
    int s0 = OFF[N + i];
    int e0 = (i == N - 1) ? NNZ : OFF[N + i + 1];
    int q = s0;
    for (; q + 8 <= e0; q += 8) {
      int2 ed[8];
      #pragma unroll
      for (int m = 0; m < 8; ++m) ed[m] = cscPk[q + m];
      float l[8];
      #pragma unroll
      for (int m = 0; m < 8; ++m) l[m] = Lv[ed[m].x];
      #pragma unroll
      for (int m = 0; m < 8; ++m) sc += __int_as_float(ed[m].y) * l[m];
    }
    for (; q + 4 <= e0; q += 4) {
      int2 ed[4];
      #pragma unroll
      for (int m = 0; m < 4; ++m) ed[m] = cscPk[q + m];
      float l[4];
      #pragma unroll
      for (int m = 0; m < 4; ++m) l[m] = Lv[ed[m].x];
      #pragma unroll
      for (int m = 0; m < 4; ++m) sc += __int_as_float(ed[m].y) * l[m];
    }
    for (; q < e0; ++q) {
      int2 ed = cscPk[q];
      sc += __int_as_float(ed.y) * Lv[ed.x];
    }
  }
  float pi = p[i];
  float Ap = diag_ku[i] * pi + rs_cm[i] * Lv[i] - sc + tg;
  x[i] += alpha * pi;
  float rn = r[i] - alpha * Ap;
  r[i] = rn;
  float v = blockReduce256(rn * rn);
  if (threadIdx.x == 0) atomicAdd(rs_t1, v);
}

__global__ void k_it3(float* __restrict__ p, const float* __restrict__ r,
                      const float* __restrict__ rs_new, const float* __restrict__ rs_old, int N)
{
  int i = blockIdx.x * TPB + threadIdx.x;
  float beta = rs_new[0] / rs_old[0];
  p[i] = r[i] + beta * p[i];
}

extern "C" void kernel_launch(void* const* d_in, const int* in_sizes, int n_in,
                              void* d_out, int out_size, void* d_ws, size_t ws_size,
                              hipStream_t stream)
{
  const float* CMw       = (const float*)d_in[0];
  const float* LOCw      = (const float*)d_in[1];
  const float* IUw       = (const float*)d_in[2];
  const float* KUw       = (const float*)d_in[3];
  const float* lmbda     = (const float*)d_in[4];
  const float* kToUconf  = (const float*)d_in[5];
  const float* known     = (const float*)d_in[6];
  const float* kToU      = (const float*)d_in[7];
  const float* Wcm_data  = (const float*)d_in[8];
  float*       LOC_flows = (float*)d_in[9];      // overwritten in-place by k_prep;
                                                 // harness restores d_in every launch
  const float* IU_flows  = (const float*)d_in[10];
  const int*   Wrow      = (const int*)d_in[11];
  const int*   Wcol      = (const int*)d_in[12];
  const int*   LOC_inInd = (const int*)d_in[13];
  const int*   IU_inInd  = (const int*)d_in[14];
  const int*   IU_neighInd = (const int*)d_in[15];
  const int*   width_p   = (const int*)d_in[16];
  const int CG_STEPS = 30;

  const int N    = in_sizes[0];      // 147456 (% 256 == 0)
  const int NNZ  = in_sizes[8];      // 1474560
  const int NLOC = in_sizes[13];     // 73728

  // ---- workspace layout, ~40.8 MB ----
  float* x       = (float*)d_out;
  float* r       = (float*)d_ws;                 // N
  float* p       = r + N;                        // N
  float* Lv      = p + N;                        // N
  float* rs_cm   = Lv + N;                       // N
  float* diag_ku = rs_cm + N;                    // N
  int2*  csrPk   = (int2*)(diag_ku + N);         // NNZ int2
  int2*  cscPk   = csrPk + (size_t)NNZ;          // NNZ int2
  int*   gU      = (int*)(cscPk + (size_t)NNZ);  // 15*NLOC
  int*   OFF     = gU + (size_t)15 * NLOC;       // 3N (in-place CNT -> OFF)
  unsigned short* tr = (unsigned short*)(OFF + (size_t)3 * N);  // NNZ u16
  unsigned short* tc = tr + (size_t)NNZ;         // NNZ u16
  unsigned short* tU = tc + (size_t)NNZ;         // 15*NLOC u16
  float* u_all   = (float*)tr;                   // 15*NLOC floats, aliases tickets
                                                 // (tickets dead after k_fill)
  int*   bsum    = (int*)(tU + (size_t)15 * NLOC);  // 3*(N/256)
  float* scal    = (float*)(bsum + 3 * (N / TPB));  // 80 floats

  const int Bn = N / TPB;        // 576
  const int Bz = NNZ / TPB;      // 5760
  const int Bl = NLOC / TPB;     // 288
  const int Z3 = 3 * Bn;

  k_init0<<<Z3, TPB, 0, stream>>>(KUw, kToUconf, lmbda, known, kToU,
                                  diag_ku, r, p, x, OFF, scal, N);
  k_prep<<<Bl, TPB, 0, stream>>>(LOC_flows, LOC_inInd, LOCw, NLOC);
  k_hist<<<Bz + 2 * Bl, TPB, 0, stream>>>(Wrow, Wcol, LOC_inInd, width_p,
                                          IU_inInd, IU_neighInd, OFF,
                                          tr, tc, tU, NLOC, N, Bz, Bz + Bl);
  k_scan1<<<Z3, TPB, 0, stream>>>(OFF, bsum, 3 * N);
  k_scan2<<<3, 1024, 0, stream>>>(bsum, Bn);
  k_scan3<<<Z3, TPB, 0, stream>>>(OFF, bsum, 3 * N);
  k_fill<<<Bz + 2 * Bl, TPB, 0, stream>>>(CMw, Wcm_data, Wrow, Wcol,
                                          LOC_inInd, width_p, IU_inInd, IU_neighInd,
                                          OFF, tr, tc, tU,
                                          csrPk, cscPk, gU,
                                          NLOC, N, Bz, Bz + Bl);

  for (int t = 0; t < CG_STEPS; ++t) {
    k_it1<<<2 * Bl + Bn, TPB, 0, stream>>>(
        p, LOC_flows, LOC_inInd, width_p,
        IU_flows, IU_inInd, IU_neighInd, IUw,
        diag_ku, OFF, csrPk, u_all, Lv, rs_cm, scal + 40 + t,
        NNZ, NLOC, N, Bl, 2 * Bl);
    k_it2<<<Bn, TPB, 0, stream>>>(
        x, r, p, Lv, rs_cm, diag_ku, OFF, cscPk, gU, u_all,
        scal + t, scal + 40 + t, scal + t + 1, NNZ, NLOC, N);
    if (t + 1 < CG_STEPS)
      k_it3<<<Bn, TPB, 0, stream>>>(p, r, scal + t + 1, scal + t, N);
  }
}